// Round 5
// baseline (2871.178 us; speedup 1.0000x reference)
//
#include <hip/hip_runtime.h>
#include <cstdint>

// ---------------------------------------------------------------------------
// QLoRA block: 4 big bf16-MFMA GEMMs + NF4 dequant + lora folded as extra K.
// M=4096 tokens, H=4096, I=14336, R=16. All bf16 handled as unsigned short.
// R6 (2nd resubmit; two broker timeouts in a row — kernel has never run):
//     exact R4 core (verified green: 2823us) + ONE delta: XCD-banded bijective
//     remap of the GEMM tile range only. GEMM blocks l in [0, NY*16) map to
//     c=l&7 (XCD, round-robin dispatch [m157/m192]), by=c*(NY/8)+(s>>4),
//     bx=s&15 -> each XCD owns a contiguous by-band; 16 consecutive blocks
//     share one B-panel in ONE L2 (was: panel replicated into 8 L2s ->
//     HBM-latency staging misses; G3 measured 39% MfmaUtil, 16% HBM).
//     Dequant ride-alongs stay EXACTLY as R4: blockIdx.y >= NY tail blocks.
//     Core schedule (T2+T3+T4+T5) unchanged: 256x256 tile, BK=64, 8 waves,
//     128 KiB LDS, counted vmcnt(4) at phases 4/8 only.
// ---------------------------------------------------------------------------

typedef __attribute__((ext_vector_type(4))) float f32x4;
typedef __attribute__((ext_vector_type(8))) short s16x8;
typedef __attribute__((ext_vector_type(4))) int   i32x4;

__constant__ float NF4_TBL[16] = {
  -1.0f, -0.6961928009986877f, -0.5250730514526367f, -0.39491748809814453f,
  -0.28444138169288635f, -0.18477343022823334f, -0.09105003625154495f, 0.0f,
   0.07958029955625534f, 0.16093020141124725f, 0.24611230194568634f,
   0.33791524171829224f, 0.44070982933044434f, 0.5626170039176941f,
   0.7229568362236023f, 1.0f };

__device__ __forceinline__ unsigned short f2bf(float f){
  unsigned u = __builtin_bit_cast(unsigned, f);
  u += 0x7fffu + ((u >> 16) & 1u);              // RNE
  return (unsigned short)(u >> 16);
}
__device__ __forceinline__ float bf2f(unsigned short h){
  return __builtin_bit_cast(float, ((unsigned)h) << 16);
}

// async global->LDS, 16B per lane. LDS dst must be wave-uniform base (lane*16 implicit).
__device__ __forceinline__ void gll16(const unsigned short* g, unsigned short* l){
  __builtin_amdgcn_global_load_lds((__attribute__((address_space(1))) unsigned int*)g,
                                   (__attribute__((address_space(3))) unsigned int*)l,
                                   16, 0, 0);
}

// ---------------------------------------------------------------------------
// NF4 dequant job descriptor (run by ride-along blocks inside gemm launches).
// ilv=1: dst row n <- plane (n&1), source row (n>>1)  [gate/up interleave]
struct DeqP {
  unsigned short* dst;
  const int* c0; const int* c1;
  const float* s0; const float* s1;
  int K; int rows; int ilv;
};

__device__ void deq_rows(const DeqP& p, int bid, int nb){
  const int K8 = p.K >> 3;
  for (int n = bid; n < p.rows; n += nb){
    const int plane = p.ilv ? (n & 1) : 0;
    const int sr    = p.ilv ? (n >> 1) : n;
    const int*   cp = (plane ? p.c1 : p.c0) + (size_t)sr * p.K;
    const float* sp = (plane ? p.s1 : p.s0) + (size_t)sr * (p.K >> 6);
    unsigned short* dp = p.dst + (size_t)n * p.K;
    for (int k8 = threadIdx.x; k8 < K8; k8 += 512){
      const int k = k8 * 8;
      const float s = sp[k >> 6];
      const i32x4 c0 = *(const i32x4*)(cp + k);
      const i32x4 c1 = *(const i32x4*)(cp + k + 4);
      s16x8 o;
      o[0]=(short)f2bf(NF4_TBL[c0.x]*s); o[1]=(short)f2bf(NF4_TBL[c0.y]*s);
      o[2]=(short)f2bf(NF4_TBL[c0.z]*s); o[3]=(short)f2bf(NF4_TBL[c0.w]*s);
      o[4]=(short)f2bf(NF4_TBL[c1.x]*s); o[5]=(short)f2bf(NF4_TBL[c1.y]*s);
      o[6]=(short)f2bf(NF4_TBL[c1.z]*s); o[7]=(short)f2bf(NF4_TBL[c1.w]*s);
      *(s16x8*)(dp + k) = o;
    }
  }
}

// ---------------------------------------------------------------------------
// elementwise fp32 -> bf16 (8 elems/thread)
__global__ void cast_f32_bf16(unsigned short* __restrict__ dst,
                              const float* __restrict__ src, long long n8){
  const long long i = (long long)blockIdx.x * blockDim.x + threadIdx.x;
  if (i >= n8) return;
  const f32x4 a = *(const f32x4*)(src + i*8);
  const f32x4 b = *(const f32x4*)(src + i*8 + 4);
  s16x8 o;
  o[0]=(short)f2bf(a.x); o[1]=(short)f2bf(a.y); o[2]=(short)f2bf(a.z); o[3]=(short)f2bf(a.w);
  o[4]=(short)f2bf(b.x); o[5]=(short)f2bf(b.y); o[6]=(short)f2bf(b.z); o[7]=(short)f2bf(b.w);
  *(s16x8*)(dst + i*8) = o;
}

// pack lora B [N,16] fp32 -> bf16 [N*rmul+radd, 64] at column offset
__global__ void pack_bl_kernel(unsigned short* __restrict__ dst,
                               const float* __restrict__ src,
                               int N, int coloff, float mul, int rmul, int radd){
  const int i = blockIdx.x * blockDim.x + threadIdx.x;
  if (i >= N * 16) return;
  const int n = i >> 4, r = i & 15;
  dst[(size_t)(n * rmul + radd) * 64 + coloff + r] = f2bf(src[i] * mul);
}

// Wsum = (Wq + Wk + Wv) * mul, dequantized on the fly (H=4096 hardcoded strides)
__global__ void dequant3_kernel(unsigned short* __restrict__ dst,
                                const int* __restrict__ codes,
                                const float* __restrict__ scales, int K, float mul){
  const int k = (blockIdx.x * blockDim.x + threadIdx.x) * 8;
  if (k >= K) return;
  const size_t n = blockIdx.y;
  const size_t base = n * (size_t)K + k;
  const size_t CS = (size_t)4096 * 4096;
  const size_t SS = (size_t)4096 * 64;
  float acc[8] = {0.f,0.f,0.f,0.f,0.f,0.f,0.f,0.f};
  #pragma unroll
  for (int t = 0; t < 3; ++t){
    const float s = scales[t * SS + n * (size_t)(K >> 6) + (k >> 6)];
    const i32x4 c0 = *(const i32x4*)(codes + t * CS + base);
    const i32x4 c1 = *(const i32x4*)(codes + t * CS + base + 4);
    acc[0]+=NF4_TBL[c0.x]*s; acc[1]+=NF4_TBL[c0.y]*s; acc[2]+=NF4_TBL[c0.z]*s; acc[3]+=NF4_TBL[c0.w]*s;
    acc[4]+=NF4_TBL[c1.x]*s; acc[5]+=NF4_TBL[c1.y]*s; acc[6]+=NF4_TBL[c1.z]*s; acc[7]+=NF4_TBL[c1.w]*s;
  }
  s16x8 o;
  #pragma unroll
  for (int e = 0; e < 8; ++e) o[e] = (short)f2bf(acc[e] * mul);
  *(s16x8*)(dst + base) = o;
}

// ---------------------------------------------------------------------------
// t = act[M,K] @ Ab[NP*16,K]^T -> tout[M,64] bf16, panel p lands at cols
// [coloff+16p, ...). Split-K: one block per 16-row M-tile (grid=M/16),
// 4 waves each take K/4, LDS-reduce partials.
template<int NP>
__global__ __launch_bounds__(256)
void lora_t_kernel(const unsigned short* __restrict__ act,
                   const unsigned short* __restrict__ Ab,
                   unsigned short* __restrict__ tout, int K, int coloff){
  __shared__ float red[4][NP][4][64];
  const int tid = threadIdx.x, lane = tid & 63, wave = tid >> 6;
  const int m0 = blockIdx.x * 16;
  const int q = lane >> 4, r = lane & 15;
  const int KW = K >> 2;                 // per-wave K chunk
  const int kbase = wave * KW;
  const unsigned short* ap = act + (size_t)(m0 + r) * K + kbase + q * 8;
  const unsigned short* bp[NP];
  #pragma unroll
  for (int p = 0; p < NP; ++p)
    bp[p] = Ab + (size_t)(p * 16 + r) * K + kbase + q * 8;
  f32x4 acc[NP];
  #pragma unroll
  for (int p = 0; p < NP; ++p) acc[p] = (f32x4){0.f,0.f,0.f,0.f};
  for (int k = 0; k < KW; k += 32){
    const s16x8 a = *(const s16x8*)ap; ap += 32;
    #pragma unroll
    for (int p = 0; p < NP; ++p){
      const s16x8 b = *(const s16x8*)bp[p]; bp[p] += 32;
      acc[p] = __builtin_amdgcn_mfma_f32_16x16x32_bf16(a, b, acc[p], 0, 0, 0);
    }
  }
  #pragma unroll
  for (int p = 0; p < NP; ++p)
    #pragma unroll
    for (int rr = 0; rr < 4; ++rr) red[wave][p][rr][lane] = acc[p][rr];
  __syncthreads();
  // D layout: row m = (lane>>4)*4 + reg, col = lane&15 [measured m89]
  const int rr = tid >> 6, li = tid & 63;
  #pragma unroll
  for (int p = 0; p < NP; ++p){
    const float v = red[0][p][rr][li] + red[1][p][rr][li]
                  + red[2][p][rr][li] + red[3][p][rr][li];
    const int row = m0 + (li >> 4) * 4 + rr;
    const int col = coloff + p * 16 + (li & 15);
    tout[(size_t)row * 64 + col] = f2bf(v);
  }
}

// ---------------------------------------------------------------------------
// 16 MFMAs of one C-quadrant (MQ selects m-frags 4MQ..4MQ+3, NQ n-frags
// 2NQ..2NQ+1), K=64 (kk=0,1). Template ints keep acc indexing compile-time.
template<int MQ, int NQ>
__device__ __forceinline__ void mfma_quad(f32x4 (&acc)[8][4],
                                          const s16x8 (&a)[4][2],
                                          const s16x8 (&b)[2][2]){
  #pragma unroll
  for (int bi = 0; bi < 2; ++bi)
    #pragma unroll
    for (int fi = 0; fi < 4; ++fi)
      #pragma unroll
      for (int kk = 0; kk < 2; ++kk)
        acc[MQ*4+fi][NQ*2+bi] = __builtin_amdgcn_mfma_f32_16x16x32_bf16(
            a[fi][kk], b[bi][kk], acc[MQ*4+fi][NQ*2+bi], 0, 0, 0);
}

// ---------------------------------------------------------------------------
// Main GEMM: C[M,N] = A[M,K] @ B[N,K]^T, bf16 in / fp32 acc.
// 256x256 tile, 512 thr = 8 waves (2Mx4N), wave does 128x64 via 8x4 mfma
// 16x16x32. BK=64; lora = one extra K=64 tile from tL[M,64]/bL[N,64].
//
// LDS regions (16KB each, 4 per operand = 2 dbuf x 2 slabs); 16B-chunk XOR
// swizzle (pre-swizzled global source, linear global_load_lds dest).
//
// 8-phase schedule per 2 K-tiles (quad order (0,0),(0,1),(1,1),(1,0)),
// counted vmcnt(4) at phases 4/8 only; every stage targets the region last
// read in the previous phase (trailing barrier separates).
//
// Blocks with blockIdx.y >= NY run NF4 dequant jobs instead (tail-fill,
// exactly as R4). GEMM blocks (y < NY) get an XCD-banded bijective remap:
// l = y*16+x in [0, NY*16); c = l&7 (XCD via round-robin dispatch), band
// by = c*(NY/8) + ((l>>3)>>4), bx = (l>>3)&15. 16 consecutive blocks on one
// XCD share one B-panel -> panel lives in ONE L2 (requires NY % 8 == 0).
//
// EPI: 0 = store bf16; 1 = x1 = res + v (fp32+bf16); 2 = out = res + v (fp32);
//      3 = gate/up interleaved -> h = silu(g)*u, bf16, h-col = gn/2.
template<int EPI>
__global__ __launch_bounds__(512, 2)
void gemm256_kernel(const unsigned short* __restrict__ Aact,
                    const unsigned short* __restrict__ Bw,
                    const unsigned short* __restrict__ tL,
                    const unsigned short* __restrict__ bL,
                    int K, int ldC,
                    const float* __restrict__ resIn,
                    float* __restrict__ outF,
                    unsigned short* __restrict__ outB,
                    int NY, DeqP dqa, DeqP dqb){
  if ((int)blockIdx.y >= NY){
    const int bid = ((int)blockIdx.y - NY) * gridDim.x + blockIdx.x;
    const int nb  = ((int)gridDim.y - NY) * gridDim.x;
    if (dqa.rows) deq_rows(dqa, bid, nb);
    if (dqb.rows) deq_rows(dqb, bid, nb);
    return;
  }
  __shared__ unsigned short As[4 * 8192];   // 4 regions x [128][64] bf16
  __shared__ unsigned short Bs[4 * 8192];
  const int tid  = threadIdx.x;
  const int lane = tid & 63;
  const int wave = tid >> 6;
  const int wm = wave >> 2, wn = wave & 3;
  const int q = lane >> 4, r15 = lane & 15;
  // XCD-banded remap of the GEMM tile range (pure bijection on [0, NY*16)).
  const int l  = (int)blockIdx.y * (int)gridDim.x + (int)blockIdx.x;
  const int c8 = l & 7, sl = l >> 3;
  const int by = c8 * (NY >> 3) + (sl >> 4);
  const int bx = sl & 15;
  const int m0 = bx << 8;
  const int n0 = by << 8;

  const int nK = K >> 6;
  const int NT = nK + 1;            // + lora tile

  // ---- staging constants: chunk c = p*512+tid; lr = c>>3, slot = c&7 ----
  const int lr0  = tid >> 3;                     // 0..63 (p=1 adds 64)
  const int dc8  = ((tid & 7) ^ (lr0 & 7)) * 8;  // swizzled data col (shorts)
  const int ldsW = wave * 512;                   // wave chunk base (shorts)
  const int grB0 = (lr0 >> 5) * 64 + (lr0 & 31);

  auto stA = [&](int s, int db, int tt){
    const int gr = m0 + s * 64 + lr0;            // p=1 row = gr + 128
    const unsigned short* p; int ld;
    if (tt < nK){ p = Aact + (size_t)gr * K + (size_t)tt * 64 + dc8; ld = K; }
    else        { p = tL   + (size_t)gr * 64 + dc8;                  ld = 64; }
    unsigned short* d = As + (db * 2 + s) * 8192 + ldsW;
    gll16(p, d);
    gll16(p + (size_t)128 * ld, d + 4096);
  };
  auto stB = [&](int s, int db, int tt){
    const int gr = n0 + s * 32 + grB0;           // p=1 row = gr + 128
    const unsigned short* p; int ld;
    if (tt < nK){ p = Bw + (size_t)gr * K + (size_t)tt * 64 + dc8; ld = K; }
    else        { p = bL + (size_t)gr * 64 + dc8;                  ld = 64; }
    unsigned short* d = Bs + (db * 2 + s) * 8192 + ldsW;
    gll16(p, d);
    gll16(p + (size_t)128 * ld, d + 4096);
  };

  // ---- fragment read constants ----
  int arow[4], brow[2];
  #pragma unroll
  for (int i = 0; i < 4; ++i) arow[i] = (wm * 64 + i * 16 + r15) * 64;
  #pragma unroll
  for (int i = 0; i < 2; ++i) brow[i] = (wn * 32 + i * 16 + r15) * 64;
  const int swz0 = (q ^ (r15 & 7)) * 8;
  const int swz1 = ((4 + q) ^ (r15 & 7)) * 8;

  s16x8 a[4][2], b[2][2];
  auto loadA = [&](int mq, int db){
    const unsigned short* base = As + (db * 2 + mq) * 8192;
    #pragma unroll
    for (int fi = 0; fi < 4; ++fi){
      a[fi][0] = *(const s16x8*)(base + arow[fi] + swz0);
      a[fi][1] = *(const s16x8*)(base + arow[fi] + swz1);
    }
  };
  auto loadB = [&](int nq, int db){
    const unsigned short* base = Bs + (db * 2 + nq) * 8192;
    #pragma unroll
    for (int bi = 0; bi < 2; ++bi){
      b[bi][0] = *(const s16x8*)(base + brow[bi] + swz0);
      b[bi][1] = *(const s16x8*)(base + brow[bi] + swz1);
    }
  };

  f32x4 acc[8][4];
  #pragma unroll
  for (int i = 0; i < 8; ++i)
    #pragma unroll
    for (int j = 0; j < 4; ++j) acc[i][j] = (f32x4){0.f, 0.f, 0.f, 0.f};

  // ---- prologue: t0 {S0,Q0,Q1,S1} + t1 {S0,Q1}; wait t0 (4 newest in flight)
  stA(0, 0, 0); stB(0, 0, 0); stB(1, 0, 0); stA(1, 0, 0);
  stA(0, 1, 1); stB(1, 1, 1);
  asm volatile("s_waitcnt vmcnt(4)" ::: "memory");
  __builtin_amdgcn_s_barrier();

#define PHASE_COMPUTE(MQ, NQ)                \
  __builtin_amdgcn_s_barrier();              \
  __builtin_amdgcn_s_setprio(1);             \
  mfma_quad<MQ, NQ>(acc, a, b);              \
  __builtin_amdgcn_s_setprio(0)

  for (int t = 0; t + 1 < NT; t += 2){
    const int u2 = t + 2, u3 = t + 3;
    const bool h2 = u2 < NT, h3 = u3 < NT;

    // ---- tile t (buf 0) ----
    loadA(0, 0); loadB(0, 0);
    stA(1, 1, t + 1);
    PHASE_COMPUTE(0, 0);
    __builtin_amdgcn_s_barrier();

    loadB(1, 0);
    stB(0, 1, t + 1);
    PHASE_COMPUTE(0, 1);
    __builtin_amdgcn_s_barrier();

    loadA(1, 0);
    if (h2) stA(0, 0, u2);
    PHASE_COMPUTE(1, 1);
    __builtin_amdgcn_s_barrier();

    loadB(0, 0);
    if (h2) stB(1, 0, u2);
    PHASE_COMPUTE(1, 0);
    if (h2) asm volatile("s_waitcnt vmcnt(4)" ::: "memory");
    else    asm volatile("s_waitcnt vmcnt(0)" ::: "memory");
    __builtin_amdgcn_s_barrier();

    // ---- tile t+1 (buf 1) ----
    loadA(0, 1); loadB(0, 1);
    if (h2) stA(1, 0, u2);
    PHASE_COMPUTE(0, 0);
    __builtin_amdgcn_s_barrier();

    loadB(1, 1);
    if (h2) stB(0, 0, u2);
    PHASE_COMPUTE(0, 1);
    __builtin_amdgcn_s_barrier();

    loadA(1, 1);
    if (h3) stA(0, 1, u3);
    PHASE_COMPUTE(1, 1);
    __builtin_amdgcn_s_barrier();

    loadB(0, 1);
    if (h3) stB(1, 1, u3);
    PHASE_COMPUTE(1, 0);
    if (h3) asm volatile("s_waitcnt vmcnt(4)" ::: "memory");
    else    asm volatile("s_waitcnt vmcnt(0)" ::: "memory");
    __builtin_amdgcn_s_barrier();
  }
#undef PHASE_COMPUTE

  // ---- tail tile (NT odd -> tile NT-1 in buf 0, fully landed) ----
  if (NT & 1){
    loadA(0, 0); loadB(0, 0); mfma_quad<0, 0>(acc, a, b);
    loadB(1, 0);              mfma_quad<0, 1>(acc, a, b);
    loadA(1, 0);              mfma_quad<1, 1>(acc, a, b);
    loadB(0, 0);              mfma_quad<1, 0>(acc, a, b);
  }

  // ---- epilogue: D row m = q*4+reg, col n = lane&15 [measured m89] ----
  #pragma unroll
  for (int fi = 0; fi < 8; ++fi){
    const int gm = m0 + wm * 128 + fi * 16 + q * 4;
    #pragma unroll
    for (int bi = 0; bi < 4; ++bi){
      const int gn = n0 + wn * 64 + bi * 16 + r15;
      #pragma unroll
      for (int rr = 0; rr < 4; ++rr){
        const float v = acc[fi][bi][rr];
        if constexpr (EPI == 3){
          // gate/up pair in adjacent lanes: even lane = gate, odd = up
          const float other = __shfl_xor(v, 1);
          if ((r15 & 1) == 0){
            const float sg = v / (1.f + __expf(-v));
            outB[(size_t)(gm + rr) * ldC + (gn >> 1)] = f2bf(sg * other);
          }
        } else {
          const size_t idx = (size_t)(gm + rr) * ldC + gn;
          if constexpr (EPI == 0){
            outB[idx] = f2bf(v);
          } else if constexpr (EPI == 1){
            const float x1 = resIn[idx] + v;
            outF[idx] = x1;
            outB[idx] = f2bf(x1);
          } else {
            outF[idx] = resIn[idx] + v;
          }
        }
      }
    }
  }
}

// ---------------------------------------------------------------------------
extern "C" void kernel_launch(void* const* d_in, const int* in_sizes, int n_in,
                              void* d_out, int out_size, void* d_ws, size_t ws_size,
                              hipStream_t stream){
  (void)in_sizes; (void)n_in; (void)out_size; (void)ws_size;
  constexpr int M = 4096, H = 4096, I = 14336, I2 = 28672;
  constexpr int IH = 7168;     // half of I (Wgu dequant split across G1/G2)

  const float* x            = (const float*)d_in[0];
  const int*   codes_attn   = (const int*)  d_in[1];
  const float* scales_attn  = (const float*)d_in[2];
  const int*   codes_gu     = (const int*)  d_in[3];
  const float* scales_gu    = (const float*)d_in[4];
  const int*   codes_down   = (const int*)  d_in[5];
  const float* scales_down  = (const float*)d_in[6];
  const float* lora_A_h     = (const float*)d_in[7];
  const float* lora_A_down  = (const float*)d_in[8];
  const float* lora_B_attn  = (const float*)d_in[9];
  const float* lora_B_gu    = (const float*)d_in[10];
  const float* lora_B_down  = (const float*)d_in[11];
  float* out = (float*)d_out;

  char* ws = (char*)d_ws;
  size_t off = 0;
  auto take = [&](size_t b){ void* p = ws + off; off += b; return p; };
  unsigned short* xb    = (unsigned short*)take((size_t)M*H*2);    // x as bf16
  unsigned short* W1    = (unsigned short*)take((size_t)H*I*2);    // Wsum(HxH), later Wd(HxI)
  unsigned short* W2    = (unsigned short*)take((size_t)H*H*2);    // Wo (dequant rides G1)
  unsigned short* attn  = (unsigned short*)take((size_t)M*H*2);
  float*          x1f   = (float*)         take((size_t)M*H*4);
  unsigned short* x1b   = (unsigned short*)take((size_t)M*H*2);
  unsigned short* Wgu   = (unsigned short*)take((size_t)I2*H*2);   // gate/up row-interleaved
  unsigned short* hbuf  = (unsigned short*)take((size_t)M*I*2);
  unsigned short* t1    = (unsigned short*)take((size_t)M*64*2);   // zeroed arena starts here
  unsigned short* t2    = (unsigned short*)take((size_t)M*64*2);
  unsigned short* t3    = (unsigned short*)take((size_t)M*64*2);
  unsigned short* t4    = (unsigned short*)take((size_t)M*64*2);
  unsigned short* bl_at = (unsigned short*)take((size_t)H*64*2);
  unsigned short* bl_o  = (unsigned short*)take((size_t)H*64*2);
  unsigned short* bl_gu = (unsigned short*)take((size_t)I2*64*2);  // interleaved rows
  unsigned short* bl_dn = (unsigned short*)take((size_t)H*64*2);
  const size_t zbytes = (size_t)((char*)ws + off - (char*)t1);
  unsigned short* al_h  = (unsigned short*)take((size_t)6*16*H*2); // lora A (h-side) bf16
  unsigned short* al_dn = (unsigned short*)take((size_t)16*I*2);   // lora A down bf16

  // zero the t / bl arena (ws is poisoned 0xAA before every call)
  hipMemsetAsync(t1, 0, zbytes, stream);

  // casts
  cast_f32_bf16<<<dim3((M*(size_t)H/8)/256), 256, 0, stream>>>(xb, x, (long long)M*H/8);
  cast_f32_bf16<<<dim3(192), 256, 0, stream>>>(al_h,  lora_A_h,    (long long)6*16*H/8);
  cast_f32_bf16<<<dim3(112), 256, 0, stream>>>(al_dn, lora_A_down, (long long)16*I/8);

  // pack lora B panels into [N,64] bf16 (gu: row-interleaved to match Wgu)
  for (int p = 0; p < 3; ++p)
    pack_bl_kernel<<<dim3(256), 256, 0, stream>>>(bl_at, lora_B_attn + (size_t)p*H*16, H, p*16, 1.f/3.f, 1, 0);
  pack_bl_kernel<<<dim3(256), 256, 0, stream>>>(bl_o, lora_B_attn + (size_t)3*H*16, H, 0, 1.f, 1, 0);
  pack_bl_kernel<<<dim3(896), 256, 0, stream>>>(bl_gu, lora_B_gu, I, 0, 1.f, 2, 0);                    // gate -> rows 2j, cols 0-15
  pack_bl_kernel<<<dim3(896), 256, 0, stream>>>(bl_gu, lora_B_gu + (size_t)I*16, I, 16, 1.f, 2, 1);    // up   -> rows 2j+1, cols 16-31
  pack_bl_kernel<<<dim3(256), 256, 0, stream>>>(bl_dn, lora_B_down, H, 0, 1.f, 1, 0);

  // Wsum = (Wq+Wk+Wv)/3 (standalone: nothing to hide under yet)
  dequant3_kernel<<<dim3(H/2048, H), 256, 0, stream>>>(W1, codes_attn, scales_attn, H, 1.f/3.f);

  // t1 = xb @ [Aq;Ak;Av]^T  (one fused NP=3 pass; 1/3 folded into bl_at)
  lora_t_kernel<3><<<dim3(M/16), 256, 0, stream>>>(xb, al_h, t1, H, 0);

  const DeqP dq0{};  // empty
  // G1: attn = xb @ Wsum^T + lora. Rides: dequant Wo -> W2, Wgu lower half.
  {
    DeqP dWo { W2, codes_attn + (size_t)3*H*H, nullptr,
               scales_attn + (size_t)3*H*64, nullptr, H, H, 0 };
    DeqP dGuA{ Wgu, codes_gu, codes_gu + (size_t)I*H,
               scales_gu, scales_gu + (size_t)I*64, H, I, 1 };
    gemm256_kernel<0><<<dim3(16, 16 + 16), 512, 0, stream>>>(xb, W1, t1, bl_at, H, H,
                                                             nullptr, nullptr, attn, 16, dWo, dGuA);
  }

  // G2: x1 = x + attn @ Wo^T + lora. Rides: dequant Wgu upper half.
  lora_t_kernel<1><<<dim3(M/16), 256, 0, stream>>>(attn, al_h + (size_t)3*16*H, t2, H, 0);
  {
    DeqP dGuB{ Wgu + (size_t)I*H, codes_gu + (size_t)IH*H, codes_gu + (size_t)I*H + (size_t)IH*H,
               scales_gu + (size_t)IH*64, scales_gu + (size_t)I*64 + (size_t)IH*64, H, I, 1 };
    gemm256_kernel<1><<<dim3(16, 16 + 16), 512, 0, stream>>>(attn, W2, t2, bl_o, H, H,
                                                             x, x1f, x1b, 16, dGuB, dq0);
  }

  // G3: h = silu(g)*u fused epilogue over interleaved [Wg;Wu]. Rides: dequant Wd -> W1 slot.
  lora_t_kernel<2><<<dim3(M/16), 256, 0, stream>>>(x1b, al_h + (size_t)4*16*H, t3, H, 0);
  {
    DeqP dWd { W1, codes_down, nullptr, scales_down, nullptr, I, H, 0 };
    gemm256_kernel<3><<<dim3(16, 112 + 16), 512, 0, stream>>>(x1b, Wgu, t3, bl_gu, H, I,
                                                              nullptr, nullptr, hbuf, 112, dWd, dq0);
  }

  // G5: out = x1 + h @ Wd^T + lora
  lora_t_kernel<1><<<dim3(M/16), 256, 0, stream>>>(hbuf, al_dn, t4, I, 0);
  gemm256_kernel<2><<<dim3(16, 16), 512, 0, stream>>>(hbuf, W1, t4, bl_dn, I, H,
                                                      x1f, out, nullptr, 16, dq0, dq0);
}

// Round 7
// 2779.166 us; speedup vs baseline: 1.0331x; 1.0331x over previous
//
#include <hip/hip_runtime.h>
#include <cstdint>

// ---------------------------------------------------------------------------
// QLoRA block: 4 big bf16-MFMA GEMMs + NF4 dequant + lora folded as extra K.
// M=4096 tokens, H=4096, I=14336, R=16. All bf16 handled as unsigned short.
// R7 (resubmit; broker timeout — kernel never ran):
//     revert R6 remap (identity map was faster; FETCH unchanged disproved the
//     L2-replication theory). Two deltas vs green R4:
//     (1) dual B register sets: phases 4/8 no longer re-read B-Q0 from LDS;
//         their MFMA has zero memory dependence and overlaps the vmcnt drain.
//         Stage/barrier/vmcnt schedule byte-identical to R4 (reads only move
//         earlier -> constraints loosen). +16 VGPR.
//     (2) non-temporal loads/stores in the NF4 dequant ride-alongs (and nt
//         code-loads in dequant3): stop the 235MB code stream + W stores from
//         thrashing L3 (G3 fetch excess ~660MB over ideal = L3 thrash).
//     Core schedule (T2+T3+T4+T5) unchanged: 256x256 tile, BK=64, 8 waves,
//     128 KiB LDS, counted vmcnt(4) at phases 4/8 only.
// ---------------------------------------------------------------------------

typedef __attribute__((ext_vector_type(4))) float f32x4;
typedef __attribute__((ext_vector_type(8))) short s16x8;
typedef __attribute__((ext_vector_type(4))) int   i32x4;

__constant__ float NF4_TBL[16] = {
  -1.0f, -0.6961928009986877f, -0.5250730514526367f, -0.39491748809814453f,
  -0.28444138169288635f, -0.18477343022823334f, -0.09105003625154495f, 0.0f,
   0.07958029955625534f, 0.16093020141124725f, 0.24611230194568634f,
   0.33791524171829224f, 0.44070982933044434f, 0.5626170039176941f,
   0.7229568362236023f, 1.0f };

__device__ __forceinline__ unsigned short f2bf(float f){
  unsigned u = __builtin_bit_cast(unsigned, f);
  u += 0x7fffu + ((u >> 16) & 1u);              // RNE
  return (unsigned short)(u >> 16);
}
__device__ __forceinline__ float bf2f(unsigned short h){
  return __builtin_bit_cast(float, ((unsigned)h) << 16);
}

// async global->LDS, 16B per lane. LDS dst must be wave-uniform base (lane*16 implicit).
__device__ __forceinline__ void gll16(const unsigned short* g, unsigned short* l){
  __builtin_amdgcn_global_load_lds((__attribute__((address_space(1))) unsigned int*)g,
                                   (__attribute__((address_space(3))) unsigned int*)l,
                                   16, 0, 0);
}

// ---------------------------------------------------------------------------
// NF4 dequant job descriptor (run by ride-along blocks inside gemm launches).
// ilv=1: dst row n <- plane (n&1), source row (n>>1)  [gate/up interleave]
struct DeqP {
  unsigned short* dst;
  const int* c0; const int* c1;
  const float* s0; const float* s1;
  int K; int rows; int ilv;
};

__device__ void deq_rows(const DeqP& p, int bid, int nb){
  const int K8 = p.K >> 3;
  for (int n = bid; n < p.rows; n += nb){
    const int plane = p.ilv ? (n & 1) : 0;
    const int sr    = p.ilv ? (n >> 1) : n;
    const int*   cp = (plane ? p.c1 : p.c0) + (size_t)sr * p.K;
    const float* sp = (plane ? p.s1 : p.s0) + (size_t)sr * (p.K >> 6);
    unsigned short* dp = p.dst + (size_t)n * p.K;
    for (int k8 = threadIdx.x; k8 < K8; k8 += 512){
      const int k = k8 * 8;
      const float s = sp[k >> 6];
      // nt: stream codes/W past L3 -- keep L3 for the concurrent GEMM's panels
      const i32x4 c0 = __builtin_nontemporal_load((const i32x4*)(cp + k));
      const i32x4 c1 = __builtin_nontemporal_load((const i32x4*)(cp + k + 4));
      s16x8 o;
      o[0]=(short)f2bf(NF4_TBL[c0.x]*s); o[1]=(short)f2bf(NF4_TBL[c0.y]*s);
      o[2]=(short)f2bf(NF4_TBL[c0.z]*s); o[3]=(short)f2bf(NF4_TBL[c0.w]*s);
      o[4]=(short)f2bf(NF4_TBL[c1.x]*s); o[5]=(short)f2bf(NF4_TBL[c1.y]*s);
      o[6]=(short)f2bf(NF4_TBL[c1.z]*s); o[7]=(short)f2bf(NF4_TBL[c1.w]*s);
      __builtin_nontemporal_store(o, (s16x8*)(dp + k));
    }
  }
}

// ---------------------------------------------------------------------------
// elementwise fp32 -> bf16 (8 elems/thread)
__global__ void cast_f32_bf16(unsigned short* __restrict__ dst,
                              const float* __restrict__ src, long long n8){
  const long long i = (long long)blockIdx.x * blockDim.x + threadIdx.x;
  if (i >= n8) return;
  const f32x4 a = *(const f32x4*)(src + i*8);
  const f32x4 b = *(const f32x4*)(src + i*8 + 4);
  s16x8 o;
  o[0]=(short)f2bf(a.x); o[1]=(short)f2bf(a.y); o[2]=(short)f2bf(a.z); o[3]=(short)f2bf(a.w);
  o[4]=(short)f2bf(b.x); o[5]=(short)f2bf(b.y); o[6]=(short)f2bf(b.z); o[7]=(short)f2bf(b.w);
  *(s16x8*)(dst + i*8) = o;
}

// pack lora B [N,16] fp32 -> bf16 [N*rmul+radd, 64] at column offset
__global__ void pack_bl_kernel(unsigned short* __restrict__ dst,
                               const float* __restrict__ src,
                               int N, int coloff, float mul, int rmul, int radd){
  const int i = blockIdx.x * blockDim.x + threadIdx.x;
  if (i >= N * 16) return;
  const int n = i >> 4, r = i & 15;
  dst[(size_t)(n * rmul + radd) * 64 + coloff + r] = f2bf(src[i] * mul);
}

// Wsum = (Wq + Wk + Wv) * mul, dequantized on the fly (H=4096 hardcoded strides)
__global__ void dequant3_kernel(unsigned short* __restrict__ dst,
                                const int* __restrict__ codes,
                                const float* __restrict__ scales, int K, float mul){
  const int k = (blockIdx.x * blockDim.x + threadIdx.x) * 8;
  if (k >= K) return;
  const size_t n = blockIdx.y;
  const size_t base = n * (size_t)K + k;
  const size_t CS = (size_t)4096 * 4096;
  const size_t SS = (size_t)4096 * 64;
  float acc[8] = {0.f,0.f,0.f,0.f,0.f,0.f,0.f,0.f};
  #pragma unroll
  for (int t = 0; t < 3; ++t){
    const float s = scales[t * SS + n * (size_t)(K >> 6) + (k >> 6)];
    const i32x4 c0 = __builtin_nontemporal_load((const i32x4*)(codes + t * CS + base));
    const i32x4 c1 = __builtin_nontemporal_load((const i32x4*)(codes + t * CS + base + 4));
    acc[0]+=NF4_TBL[c0.x]*s; acc[1]+=NF4_TBL[c0.y]*s; acc[2]+=NF4_TBL[c0.z]*s; acc[3]+=NF4_TBL[c0.w]*s;
    acc[4]+=NF4_TBL[c1.x]*s; acc[5]+=NF4_TBL[c1.y]*s; acc[6]+=NF4_TBL[c1.z]*s; acc[7]+=NF4_TBL[c1.w]*s;
  }
  s16x8 o;
  #pragma unroll
  for (int e = 0; e < 8; ++e) o[e] = (short)f2bf(acc[e] * mul);
  *(s16x8*)(dst + base) = o;
}

// ---------------------------------------------------------------------------
// t = act[M,K] @ Ab[NP*16,K]^T -> tout[M,64] bf16, panel p lands at cols
// [coloff+16p, ...). Split-K: one block per 16-row M-tile (grid=M/16),
// 4 waves each take K/4, LDS-reduce partials.
template<int NP>
__global__ __launch_bounds__(256)
void lora_t_kernel(const unsigned short* __restrict__ act,
                   const unsigned short* __restrict__ Ab,
                   unsigned short* __restrict__ tout, int K, int coloff){
  __shared__ float red[4][NP][4][64];
  const int tid = threadIdx.x, lane = tid & 63, wave = tid >> 6;
  const int m0 = blockIdx.x * 16;
  const int q = lane >> 4, r = lane & 15;
  const int KW = K >> 2;                 // per-wave K chunk
  const int kbase = wave * KW;
  const unsigned short* ap = act + (size_t)(m0 + r) * K + kbase + q * 8;
  const unsigned short* bp[NP];
  #pragma unroll
  for (int p = 0; p < NP; ++p)
    bp[p] = Ab + (size_t)(p * 16 + r) * K + kbase + q * 8;
  f32x4 acc[NP];
  #pragma unroll
  for (int p = 0; p < NP; ++p) acc[p] = (f32x4){0.f,0.f,0.f,0.f};
  for (int k = 0; k < KW; k += 32){
    const s16x8 a = *(const s16x8*)ap; ap += 32;
    #pragma unroll
    for (int p = 0; p < NP; ++p){
      const s16x8 b = *(const s16x8*)bp[p]; bp[p] += 32;
      acc[p] = __builtin_amdgcn_mfma_f32_16x16x32_bf16(a, b, acc[p], 0, 0, 0);
    }
  }
  #pragma unroll
  for (int p = 0; p < NP; ++p)
    #pragma unroll
    for (int rr = 0; rr < 4; ++rr) red[wave][p][rr][lane] = acc[p][rr];
  __syncthreads();
  // D layout: row m = (lane>>4)*4 + reg, col = lane&15 [measured m89]
  const int rr = tid >> 6, li = tid & 63;
  #pragma unroll
  for (int p = 0; p < NP; ++p){
    const float v = red[0][p][rr][li] + red[1][p][rr][li]
                  + red[2][p][rr][li] + red[3][p][rr][li];
    const int row = m0 + (li >> 4) * 4 + rr;
    const int col = coloff + p * 16 + (li & 15);
    tout[(size_t)row * 64 + col] = f2bf(v);
  }
}

// ---------------------------------------------------------------------------
// 16 MFMAs of one C-quadrant (MQ selects m-frags 4MQ..4MQ+3, NQ n-frags
// 2NQ..2NQ+1), K=64 (kk=0,1). Template ints keep acc indexing compile-time.
template<int MQ, int NQ>
__device__ __forceinline__ void mfma_quad(f32x4 (&acc)[8][4],
                                          const s16x8 (&a)[4][2],
                                          const s16x8 (&b)[2][2]){
  #pragma unroll
  for (int bi = 0; bi < 2; ++bi)
    #pragma unroll
    for (int fi = 0; fi < 4; ++fi)
      #pragma unroll
      for (int kk = 0; kk < 2; ++kk)
        acc[MQ*4+fi][NQ*2+bi] = __builtin_amdgcn_mfma_f32_16x16x32_bf16(
            a[fi][kk], b[bi][kk], acc[MQ*4+fi][NQ*2+bi], 0, 0, 0);
}

// ---------------------------------------------------------------------------
// Main GEMM: C[M,N] = A[M,K] @ B[N,K]^T, bf16 in / fp32 acc.
// 256x256 tile, 512 thr = 8 waves (2Mx4N), wave does 128x64 via 8x4 mfma
// 16x16x32. BK=64; lora = one extra K=64 tile from tL[M,64]/bL[N,64].
//
// LDS regions (16KB each, 4 per operand = 2 dbuf x 2 slabs); 16B-chunk XOR
// swizzle (pre-swizzled global source, linear global_load_lds dest).
//
// 8-phase schedule per 2 K-tiles, quad order (0,0),(0,1),(1,1),(1,0).
// B-Q0 is read ONCE per tile (ph1) into reg set b0; B-Q1 (ph2) into b1;
// phases 4/8 compute quad(1,0) from b0 regs with NO LDS reads -> their MFMA
// overlaps the vmcnt drain. Counted vmcnt(4) at phases 4/8 only; every stage
// targets a region whose last read was >=1 barrier-pair earlier.
//
// Blocks with blockIdx.y >= NY run NF4 dequant jobs instead (tail-fill).
//
// EPI: 0 = store bf16; 1 = x1 = res + v (fp32+bf16); 2 = out = res + v (fp32);
//      3 = gate/up interleaved -> h = silu(g)*u, bf16, h-col = gn/2.
template<int EPI>
__global__ __launch_bounds__(512, 2)
void gemm256_kernel(const unsigned short* __restrict__ Aact,
                    const unsigned short* __restrict__ Bw,
                    const unsigned short* __restrict__ tL,
                    const unsigned short* __restrict__ bL,
                    int K, int ldC,
                    const float* __restrict__ resIn,
                    float* __restrict__ outF,
                    unsigned short* __restrict__ outB,
                    int NY, DeqP dqa, DeqP dqb){
  if ((int)blockIdx.y >= NY){
    const int bid = ((int)blockIdx.y - NY) * gridDim.x + blockIdx.x;
    const int nb  = ((int)gridDim.y - NY) * gridDim.x;
    if (dqa.rows) deq_rows(dqa, bid, nb);
    if (dqb.rows) deq_rows(dqb, bid, nb);
    return;
  }
  __shared__ unsigned short As[4 * 8192];   // 4 regions x [128][64] bf16
  __shared__ unsigned short Bs[4 * 8192];
  const int tid  = threadIdx.x;
  const int lane = tid & 63;
  const int wave = tid >> 6;
  const int wm = wave >> 2, wn = wave & 3;
  const int q = lane >> 4, r15 = lane & 15;
  const int m0 = blockIdx.x << 8;   // x = M tiles so consecutive blocks share B-panel
  const int n0 = blockIdx.y << 8;

  const int nK = K >> 6;
  const int NT = nK + 1;            // + lora tile

  // ---- staging constants: chunk c = p*512+tid; lr = c>>3, slot = c&7 ----
  const int lr0  = tid >> 3;                     // 0..63 (p=1 adds 64)
  const int dc8  = ((tid & 7) ^ (lr0 & 7)) * 8;  // swizzled data col (shorts)
  const int ldsW = wave * 512;                   // wave chunk base (shorts)
  const int grB0 = (lr0 >> 5) * 64 + (lr0 & 31);

  auto stA = [&](int s, int db, int tt){
    const int gr = m0 + s * 64 + lr0;            // p=1 row = gr + 128
    const unsigned short* p; int ld;
    if (tt < nK){ p = Aact + (size_t)gr * K + (size_t)tt * 64 + dc8; ld = K; }
    else        { p = tL   + (size_t)gr * 64 + dc8;                  ld = 64; }
    unsigned short* d = As + (db * 2 + s) * 8192 + ldsW;
    gll16(p, d);
    gll16(p + (size_t)128 * ld, d + 4096);
  };
  auto stB = [&](int s, int db, int tt){
    const int gr = n0 + s * 32 + grB0;           // p=1 row = gr + 128
    const unsigned short* p; int ld;
    if (tt < nK){ p = Bw + (size_t)gr * K + (size_t)tt * 64 + dc8; ld = K; }
    else        { p = bL + (size_t)gr * 64 + dc8;                  ld = 64; }
    unsigned short* d = Bs + (db * 2 + s) * 8192 + ldsW;
    gll16(p, d);
    gll16(p + (size_t)128 * ld, d + 4096);
  };

  // ---- fragment read constants ----
  int arow[4], brow[2];
  #pragma unroll
  for (int i = 0; i < 4; ++i) arow[i] = (wm * 64 + i * 16 + r15) * 64;
  #pragma unroll
  for (int i = 0; i < 2; ++i) brow[i] = (wn * 32 + i * 16 + r15) * 64;
  const int swz0 = (q ^ (r15 & 7)) * 8;
  const int swz1 = ((4 + q) ^ (r15 & 7)) * 8;

  s16x8 a[4][2], b0[2][2], b1[2][2];
  auto loadA = [&](int mq, int db){
    const unsigned short* base = As + (db * 2 + mq) * 8192;
    #pragma unroll
    for (int fi = 0; fi < 4; ++fi){
      a[fi][0] = *(const s16x8*)(base + arow[fi] + swz0);
      a[fi][1] = *(const s16x8*)(base + arow[fi] + swz1);
    }
  };
  auto loadB = [&](int nq, int db, s16x8 (&bb)[2][2]){
    const unsigned short* base = Bs + (db * 2 + nq) * 8192;
    #pragma unroll
    for (int bi = 0; bi < 2; ++bi){
      bb[bi][0] = *(const s16x8*)(base + brow[bi] + swz0);
      bb[bi][1] = *(const s16x8*)(base + brow[bi] + swz1);
    }
  };

  f32x4 acc[8][4];
  #pragma unroll
  for (int i = 0; i < 8; ++i)
    #pragma unroll
    for (int j = 0; j < 4; ++j) acc[i][j] = (f32x4){0.f, 0.f, 0.f, 0.f};

  // ---- prologue: t0 {S0,Q0,Q1,S1} + t1 {S0,Q1}; wait t0 (4 newest in flight)
  stA(0, 0, 0); stB(0, 0, 0); stB(1, 0, 0); stA(1, 0, 0);
  stA(0, 1, 1); stB(1, 1, 1);
  asm volatile("s_waitcnt vmcnt(4)" ::: "memory");
  __builtin_amdgcn_s_barrier();

#define PHASE_COMPUTE(MQ, NQ, BB)            \
  __builtin_amdgcn_s_barrier();              \
  __builtin_amdgcn_s_setprio(1);             \
  mfma_quad<MQ, NQ>(acc, a, BB);             \
  __builtin_amdgcn_s_setprio(0)

  for (int t = 0; t + 1 < NT; t += 2){
    const int u2 = t + 2, u3 = t + 3;
    const bool h2 = u2 < NT, h3 = u3 < NT;

    // ---- tile t (buf 0) ----
    loadA(0, 0); loadB(0, 0, b0);
    stA(1, 1, t + 1);
    PHASE_COMPUTE(0, 0, b0);
    __builtin_amdgcn_s_barrier();

    loadB(1, 0, b1);
    stB(0, 1, t + 1);
    PHASE_COMPUTE(0, 1, b1);
    __builtin_amdgcn_s_barrier();

    loadA(1, 0);
    if (h2) stA(0, 0, u2);
    PHASE_COMPUTE(1, 1, b1);
    __builtin_amdgcn_s_barrier();

    if (h2) stB(1, 0, u2);
    PHASE_COMPUTE(1, 0, b0);                 // no LDS reads: b0 reused from regs
    if (h2) asm volatile("s_waitcnt vmcnt(4)" ::: "memory");
    else    asm volatile("s_waitcnt vmcnt(0)" ::: "memory");
    __builtin_amdgcn_s_barrier();

    // ---- tile t+1 (buf 1) ----
    loadA(0, 1); loadB(0, 1, b0);
    if (h2) stA(1, 0, u2);
    PHASE_COMPUTE(0, 0, b0);
    __builtin_amdgcn_s_barrier();

    loadB(1, 1, b1);
    if (h2) stB(0, 0, u2);
    PHASE_COMPUTE(0, 1, b1);
    __builtin_amdgcn_s_barrier();

    loadA(1, 1);
    if (h3) stA(0, 1, u3);
    PHASE_COMPUTE(1, 1, b1);
    __builtin_amdgcn_s_barrier();

    if (h3) stB(1, 1, u3);
    PHASE_COMPUTE(1, 0, b0);                 // no LDS reads
    if (h3) asm volatile("s_waitcnt vmcnt(4)" ::: "memory");
    else    asm volatile("s_waitcnt vmcnt(0)" ::: "memory");
    __builtin_amdgcn_s_barrier();
  }
#undef PHASE_COMPUTE

  // ---- tail tile (NT odd -> tile NT-1 in buf 0, fully landed) ----
  if (NT & 1){
    loadA(0, 0); loadB(0, 0, b0); mfma_quad<0, 0>(acc, a, b0);
    loadB(1, 0, b1);              mfma_quad<0, 1>(acc, a, b1);
    loadA(1, 0);                  mfma_quad<1, 1>(acc, a, b1);
                                  mfma_quad<1, 0>(acc, a, b0);
  }

  // ---- epilogue: D row m = q*4+reg, col n = lane&15 [measured m89] ----
  #pragma unroll
  for (int fi = 0; fi < 8; ++fi){
    const int gm = m0 + wm * 128 + fi * 16 + q * 4;
    #pragma unroll
    for (int bi = 0; bi < 4; ++bi){
      const int gn = n0 + wn * 64 + bi * 16 + r15;
      #pragma unroll
      for (int rr = 0; rr < 4; ++rr){
        const float v = acc[fi][bi][rr];
        if constexpr (EPI == 3){
          // gate/up pair in adjacent lanes: even lane = gate, odd = up
          const float other = __shfl_xor(v, 1);
          if ((r15 & 1) == 0){
            const float sg = v / (1.f + __expf(-v));
            outB[(size_t)(gm + rr) * ldC + (gn >> 1)] = f2bf(sg * other);
          }
        } else {
          const size_t idx = (size_t)(gm + rr) * ldC + gn;
          if constexpr (EPI == 0){
            outB[idx] = f2bf(v);
          } else if constexpr (EPI == 1){
            const float x1 = resIn[idx] + v;
            outF[idx] = x1;
            outB[idx] = f2bf(x1);
          } else {
            outF[idx] = resIn[idx] + v;
          }
        }
      }
    }
  }
}

// ---------------------------------------------------------------------------
extern "C" void kernel_launch(void* const* d_in, const int* in_sizes, int n_in,
                              void* d_out, int out_size, void* d_ws, size_t ws_size,
                              hipStream_t stream){
  (void)in_sizes; (void)n_in; (void)out_size; (void)ws_size;
  constexpr int M = 4096, H = 4096, I = 14336, I2 = 28672;
  constexpr int IH = 7168;     // half of I (Wgu dequant split across G1/G2)

  const float* x            = (const float*)d_in[0];
  const int*   codes_attn   = (const int*)  d_in[1];
  const float* scales_attn  = (const float*)d_in[2];
  const int*   codes_gu     = (const int*)  d_in[3];
  const float* scales_gu    = (const float*)d_in[4];
  const int*   codes_down   = (const int*)  d_in[5];
  const float* scales_down  = (const float*)d_in[6];
  const float* lora_A_h     = (const float*)d_in[7];
  const float* lora_A_down  = (const float*)d_in[8];
  const float* lora_B_attn  = (const float*)d_in[9];
  const float* lora_B_gu    = (const float*)d_in[10];
  const float* lora_B_down  = (const float*)d_in[11];
  float* out = (float*)d_out;

  char* ws = (char*)d_ws;
  size_t off = 0;
  auto take = [&](size_t b){ void* p = ws + off; off += b; return p; };
  unsigned short* xb    = (unsigned short*)take((size_t)M*H*2);    // x as bf16
  unsigned short* W1    = (unsigned short*)take((size_t)H*I*2);    // Wsum(HxH), later Wd(HxI)
  unsigned short* W2    = (unsigned short*)take((size_t)H*H*2);    // Wo (dequant rides G1)
  unsigned short* attn  = (unsigned short*)take((size_t)M*H*2);
  float*          x1f   = (float*)         take((size_t)M*H*4);
  unsigned short* x1b   = (unsigned short*)take((size_t)M*H*2);
  unsigned short* Wgu   = (unsigned short*)take((size_t)I2*H*2);   // gate/up row-interleaved
  unsigned short* hbuf  = (unsigned short*)take((size_t)M*I*2);
  unsigned short* t1    = (unsigned short*)take((size_t)M*64*2);   // zeroed arena starts here
  unsigned short* t2    = (unsigned short*)take((size_t)M*64*2);
  unsigned short* t3    = (unsigned short*)take((size_t)M*64*2);
  unsigned short* t4    = (unsigned short*)take((size_t)M*64*2);
  unsigned short* bl_at = (unsigned short*)take((size_t)H*64*2);
  unsigned short* bl_o  = (unsigned short*)take((size_t)H*64*2);
  unsigned short* bl_gu = (unsigned short*)take((size_t)I2*64*2);  // interleaved rows
  unsigned short* bl_dn = (unsigned short*)take((size_t)H*64*2);
  const size_t zbytes = (size_t)((char*)ws + off - (char*)t1);
  unsigned short* al_h  = (unsigned short*)take((size_t)6*16*H*2); // lora A (h-side) bf16
  unsigned short* al_dn = (unsigned short*)take((size_t)16*I*2);   // lora A down bf16

  // zero the t / bl arena (ws is poisoned 0xAA before every call)
  hipMemsetAsync(t1, 0, zbytes, stream);

  // casts
  cast_f32_bf16<<<dim3((M*(size_t)H/8)/256), 256, 0, stream>>>(xb, x, (long long)M*H/8);
  cast_f32_bf16<<<dim3(192), 256, 0, stream>>>(al_h,  lora_A_h,    (long long)6*16*H/8);
  cast_f32_bf16<<<dim3(112), 256, 0, stream>>>(al_dn, lora_A_down, (long long)16*I/8);

  // pack lora B panels into [N,64] bf16 (gu: row-interleaved to match Wgu)
  for (int p = 0; p < 3; ++p)
    pack_bl_kernel<<<dim3(256), 256, 0, stream>>>(bl_at, lora_B_attn + (size_t)p*H*16, H, p*16, 1.f/3.f, 1, 0);
  pack_bl_kernel<<<dim3(256), 256, 0, stream>>>(bl_o, lora_B_attn + (size_t)3*H*16, H, 0, 1.f, 1, 0);
  pack_bl_kernel<<<dim3(896), 256, 0, stream>>>(bl_gu, lora_B_gu, I, 0, 1.f, 2, 0);                    // gate -> rows 2j, cols 0-15
  pack_bl_kernel<<<dim3(896), 256, 0, stream>>>(bl_gu, lora_B_gu + (size_t)I*16, I, 16, 1.f, 2, 1);    // up   -> rows 2j+1, cols 16-31
  pack_bl_kernel<<<dim3(256), 256, 0, stream>>>(bl_dn, lora_B_down, H, 0, 1.f, 1, 0);

  // Wsum = (Wq+Wk+Wv)/3 (standalone: nothing to hide under yet)
  dequant3_kernel<<<dim3(H/2048, H), 256, 0, stream>>>(W1, codes_attn, scales_attn, H, 1.f/3.f);

  // t1 = xb @ [Aq;Ak;Av]^T  (one fused NP=3 pass; 1/3 folded into bl_at)
  lora_t_kernel<3><<<dim3(M/16), 256, 0, stream>>>(xb, al_h, t1, H, 0);

  const DeqP dq0{};  // empty
  // G1: attn = xb @ Wsum^T + lora. Rides: dequant Wo -> W2, Wgu lower half.
  {
    DeqP dWo { W2, codes_attn + (size_t)3*H*H, nullptr,
               scales_attn + (size_t)3*H*64, nullptr, H, H, 0 };
    DeqP dGuA{ Wgu, codes_gu, codes_gu + (size_t)I*H,
               scales_gu, scales_gu + (size_t)I*64, H, I, 1 };
    gemm256_kernel<0><<<dim3(16, 16 + 16), 512, 0, stream>>>(xb, W1, t1, bl_at, H, H,
                                                             nullptr, nullptr, attn, 16, dWo, dGuA);
  }

  // G2: x1 = x + attn @ Wo^T + lora. Rides: dequant Wgu upper half.
  lora_t_kernel<1><<<dim3(M/16), 256, 0, stream>>>(attn, al_h + (size_t)3*16*H, t2, H, 0);
  {
    DeqP dGuB{ Wgu + (size_t)I*H, codes_gu + (size_t)IH*H, codes_gu + (size_t)I*H + (size_t)IH*H,
               scales_gu + (size_t)IH*64, scales_gu + (size_t)I*64 + (size_t)IH*64, H, I, 1 };
    gemm256_kernel<1><<<dim3(16, 16 + 16), 512, 0, stream>>>(attn, W2, t2, bl_o, H, H,
                                                             x, x1f, x1b, 16, dGuB, dq0);
  }

  // G3: h = silu(g)*u fused epilogue over interleaved [Wg;Wu]. Rides: dequant Wd -> W1 slot.
  lora_t_kernel<2><<<dim3(M/16), 256, 0, stream>>>(x1b, al_h + (size_t)4*16*H, t3, H, 0);
  {
    DeqP dWd { W1, codes_down, nullptr, scales_down, nullptr, I, H, 0 };
    gemm256_kernel<3><<<dim3(16, 112 + 16), 512, 0, stream>>>(x1b, Wgu, t3, bl_gu, H, I,
                                                              nullptr, nullptr, hbuf, 112, dWd, dq0);
  }

  // G5: out = x1 + h @ Wd^T + lora
  lora_t_kernel<1><<<dim3(M/16), 256, 0, stream>>>(hbuf, al_dn, t4, I, 0);
  gemm256_kernel<2><<<dim3(16, 16), 512, 0, stream>>>(hbuf, W1, t4, bl_dn, I, H,
                                                      x1f, out, nullptr, 16, dq0, dq0);
}

// Round 9
// 2750.147 us; speedup vs baseline: 1.0440x; 1.0106x over previous
//
#include <hip/hip_runtime.h>
#include <cstdint>

// ---------------------------------------------------------------------------
// QLoRA block: 4 big bf16-MFMA GEMMs + NF4 dequant + lora folded as extra K.
// M=4096 tokens, H=4096, I=14336, R=16. All bf16 handled as unsigned short.
// R8 (resubmit; broker timeout — kernel never ran):
//     ONE delta vs green R7 (2779us): drop the pre-MFMA barrier in each phase.
//     Phase = [ds_reads | stage | setprio MFMA setprio | (vmcnt ph4/8) | barrier].
//     Rationale (cycle model from R7 counters): per K-tile, LDS reads (1536cyc)
//     and MFMA (2483cyc) were ADDITIVE under full lockstep (2 barriers/phase);
//     observed 4962 cyc/tile ~= 2483+1536+overhead. The leading barrier is
//     redundant for correctness: every stage targets a region whose reads were
//     consumed (lgkm drained into MFMA) before the PREVIOUS trailing barrier.
//     Removing it lets each wave enter MFMA on its own lgkm drain -> LDS serves
//     other waves' reads under running MFMAs; barriers halve (8->4 per tile).
//     Kept from R7: dual B register sets (ph4/8 have zero LDS reads), nt
//     dequant streams (neutral on FETCH but harmless), identity block map,
//     256x256 tile / BK=64 / 8 waves / 128KiB LDS / vmcnt(4) at ph4/8 only.
// ---------------------------------------------------------------------------

typedef __attribute__((ext_vector_type(4))) float f32x4;
typedef __attribute__((ext_vector_type(8))) short s16x8;
typedef __attribute__((ext_vector_type(4))) int   i32x4;

__constant__ float NF4_TBL[16] = {
  -1.0f, -0.6961928009986877f, -0.5250730514526367f, -0.39491748809814453f,
  -0.28444138169288635f, -0.18477343022823334f, -0.09105003625154495f, 0.0f,
   0.07958029955625534f, 0.16093020141124725f, 0.24611230194568634f,
   0.33791524171829224f, 0.44070982933044434f, 0.5626170039176941f,
   0.7229568362236023f, 1.0f };

__device__ __forceinline__ unsigned short f2bf(float f){
  unsigned u = __builtin_bit_cast(unsigned, f);
  u += 0x7fffu + ((u >> 16) & 1u);              // RNE
  return (unsigned short)(u >> 16);
}
__device__ __forceinline__ float bf2f(unsigned short h){
  return __builtin_bit_cast(float, ((unsigned)h) << 16);
}

// async global->LDS, 16B per lane. LDS dst must be wave-uniform base (lane*16 implicit).
__device__ __forceinline__ void gll16(const unsigned short* g, unsigned short* l){
  __builtin_amdgcn_global_load_lds((__attribute__((address_space(1))) unsigned int*)g,
                                   (__attribute__((address_space(3))) unsigned int*)l,
                                   16, 0, 0);
}

// ---------------------------------------------------------------------------
// NF4 dequant job descriptor (run by ride-along blocks inside gemm launches).
// ilv=1: dst row n <- plane (n&1), source row (n>>1)  [gate/up interleave]
struct DeqP {
  unsigned short* dst;
  const int* c0; const int* c1;
  const float* s0; const float* s1;
  int K; int rows; int ilv;
};

__device__ void deq_rows(const DeqP& p, int bid, int nb){
  const int K8 = p.K >> 3;
  for (int n = bid; n < p.rows; n += nb){
    const int plane = p.ilv ? (n & 1) : 0;
    const int sr    = p.ilv ? (n >> 1) : n;
    const int*   cp = (plane ? p.c1 : p.c0) + (size_t)sr * p.K;
    const float* sp = (plane ? p.s1 : p.s0) + (size_t)sr * (p.K >> 6);
    unsigned short* dp = p.dst + (size_t)n * p.K;
    for (int k8 = threadIdx.x; k8 < K8; k8 += 512){
      const int k = k8 * 8;
      const float s = sp[k >> 6];
      // nt: stream codes/W past L3 (neutral on FETCH per R7, kept as harmless)
      const i32x4 c0 = __builtin_nontemporal_load((const i32x4*)(cp + k));
      const i32x4 c1 = __builtin_nontemporal_load((const i32x4*)(cp + k + 4));
      s16x8 o;
      o[0]=(short)f2bf(NF4_TBL[c0.x]*s); o[1]=(short)f2bf(NF4_TBL[c0.y]*s);
      o[2]=(short)f2bf(NF4_TBL[c0.z]*s); o[3]=(short)f2bf(NF4_TBL[c0.w]*s);
      o[4]=(short)f2bf(NF4_TBL[c1.x]*s); o[5]=(short)f2bf(NF4_TBL[c1.y]*s);
      o[6]=(short)f2bf(NF4_TBL[c1.z]*s); o[7]=(short)f2bf(NF4_TBL[c1.w]*s);
      __builtin_nontemporal_store(o, (s16x8*)(dp + k));
    }
  }
}

// ---------------------------------------------------------------------------
// elementwise fp32 -> bf16 (8 elems/thread)
__global__ void cast_f32_bf16(unsigned short* __restrict__ dst,
                              const float* __restrict__ src, long long n8){
  const long long i = (long long)blockIdx.x * blockDim.x + threadIdx.x;
  if (i >= n8) return;
  const f32x4 a = *(const f32x4*)(src + i*8);
  const f32x4 b = *(const f32x4*)(src + i*8 + 4);
  s16x8 o;
  o[0]=(short)f2bf(a.x); o[1]=(short)f2bf(a.y); o[2]=(short)f2bf(a.z); o[3]=(short)f2bf(a.w);
  o[4]=(short)f2bf(b.x); o[5]=(short)f2bf(b.y); o[6]=(short)f2bf(b.z); o[7]=(short)f2bf(b.w);
  *(s16x8*)(dst + i*8) = o;
}

// pack lora B [N,16] fp32 -> bf16 [N*rmul+radd, 64] at column offset
__global__ void pack_bl_kernel(unsigned short* __restrict__ dst,
                               const float* __restrict__ src,
                               int N, int coloff, float mul, int rmul, int radd){
  const int i = blockIdx.x * blockDim.x + threadIdx.x;
  if (i >= N * 16) return;
  const int n = i >> 4, r = i & 15;
  dst[(size_t)(n * rmul + radd) * 64 + coloff + r] = f2bf(src[i] * mul);
}

// Wsum = (Wq + Wk + Wv) * mul, dequantized on the fly (H=4096 hardcoded strides)
__global__ void dequant3_kernel(unsigned short* __restrict__ dst,
                                const int* __restrict__ codes,
                                const float* __restrict__ scales, int K, float mul){
  const int k = (blockIdx.x * blockDim.x + threadIdx.x) * 8;
  if (k >= K) return;
  const size_t n = blockIdx.y;
  const size_t base = n * (size_t)K + k;
  const size_t CS = (size_t)4096 * 4096;
  const size_t SS = (size_t)4096 * 64;
  float acc[8] = {0.f,0.f,0.f,0.f,0.f,0.f,0.f,0.f};
  #pragma unroll
  for (int t = 0; t < 3; ++t){
    const float s = scales[t * SS + n * (size_t)(K >> 6) + (k >> 6)];
    const i32x4 c0 = __builtin_nontemporal_load((const i32x4*)(codes + t * CS + base));
    const i32x4 c1 = __builtin_nontemporal_load((const i32x4*)(codes + t * CS + base + 4));
    acc[0]+=NF4_TBL[c0.x]*s; acc[1]+=NF4_TBL[c0.y]*s; acc[2]+=NF4_TBL[c0.z]*s; acc[3]+=NF4_TBL[c0.w]*s;
    acc[4]+=NF4_TBL[c1.x]*s; acc[5]+=NF4_TBL[c1.y]*s; acc[6]+=NF4_TBL[c1.z]*s; acc[7]+=NF4_TBL[c1.w]*s;
  }
  s16x8 o;
  #pragma unroll
  for (int e = 0; e < 8; ++e) o[e] = (short)f2bf(acc[e] * mul);
  *(s16x8*)(dst + base) = o;
}

// ---------------------------------------------------------------------------
// t = act[M,K] @ Ab[NP*16,K]^T -> tout[M,64] bf16, panel p lands at cols
// [coloff+16p, ...). Split-K: one block per 16-row M-tile (grid=M/16),
// 4 waves each take K/4, LDS-reduce partials.
template<int NP>
__global__ __launch_bounds__(256)
void lora_t_kernel(const unsigned short* __restrict__ act,
                   const unsigned short* __restrict__ Ab,
                   unsigned short* __restrict__ tout, int K, int coloff){
  __shared__ float red[4][NP][4][64];
  const int tid = threadIdx.x, lane = tid & 63, wave = tid >> 6;
  const int m0 = blockIdx.x * 16;
  const int q = lane >> 4, r = lane & 15;
  const int KW = K >> 2;                 // per-wave K chunk
  const int kbase = wave * KW;
  const unsigned short* ap = act + (size_t)(m0 + r) * K + kbase + q * 8;
  const unsigned short* bp[NP];
  #pragma unroll
  for (int p = 0; p < NP; ++p)
    bp[p] = Ab + (size_t)(p * 16 + r) * K + kbase + q * 8;
  f32x4 acc[NP];
  #pragma unroll
  for (int p = 0; p < NP; ++p) acc[p] = (f32x4){0.f,0.f,0.f,0.f};
  for (int k = 0; k < KW; k += 32){
    const s16x8 a = *(const s16x8*)ap; ap += 32;
    #pragma unroll
    for (int p = 0; p < NP; ++p){
      const s16x8 b = *(const s16x8*)bp[p]; bp[p] += 32;
      acc[p] = __builtin_amdgcn_mfma_f32_16x16x32_bf16(a, b, acc[p], 0, 0, 0);
    }
  }
  #pragma unroll
  for (int p = 0; p < NP; ++p)
    #pragma unroll
    for (int rr = 0; rr < 4; ++rr) red[wave][p][rr][lane] = acc[p][rr];
  __syncthreads();
  // D layout: row m = (lane>>4)*4 + reg, col = lane&15 [measured m89]
  const int rr = tid >> 6, li = tid & 63;
  #pragma unroll
  for (int p = 0; p < NP; ++p){
    const float v = red[0][p][rr][li] + red[1][p][rr][li]
                  + red[2][p][rr][li] + red[3][p][rr][li];
    const int row = m0 + (li >> 4) * 4 + rr;
    const int col = coloff + p * 16 + (li & 15);
    tout[(size_t)row * 64 + col] = f2bf(v);
  }
}

// ---------------------------------------------------------------------------
// 16 MFMAs of one C-quadrant (MQ selects m-frags 4MQ..4MQ+3, NQ n-frags
// 2NQ..2NQ+1), K=64 (kk=0,1). Template ints keep acc indexing compile-time.
template<int MQ, int NQ>
__device__ __forceinline__ void mfma_quad(f32x4 (&acc)[8][4],
                                          const s16x8 (&a)[4][2],
                                          const s16x8 (&b)[2][2]){
  #pragma unroll
  for (int bi = 0; bi < 2; ++bi)
    #pragma unroll
    for (int fi = 0; fi < 4; ++fi)
      #pragma unroll
      for (int kk = 0; kk < 2; ++kk)
        acc[MQ*4+fi][NQ*2+bi] = __builtin_amdgcn_mfma_f32_16x16x32_bf16(
            a[fi][kk], b[bi][kk], acc[MQ*4+fi][NQ*2+bi], 0, 0, 0);
}

// ---------------------------------------------------------------------------
// Main GEMM: C[M,N] = A[M,K] @ B[N,K]^T, bf16 in / fp32 acc.
// 256x256 tile, 512 thr = 8 waves (2Mx4N), wave does 128x64 via 8x4 mfma
// 16x16x32. BK=64; lora = one extra K=64 tile from tL[M,64]/bL[N,64].
//
// LDS regions (16KB each, 4 per operand = 2 dbuf x 2 slabs); 16B-chunk XOR
// swizzle (pre-swizzled global source, linear global_load_lds dest).
//
// 4-phase-per-tile schedule, quad order (0,0),(0,1),(1,1),(1,0); ONE trailing
// barrier per phase. Safety: a stage in phase p targets a region whose reads
// were consumed (lgkm drained into that phase's MFMA) before phase p-1's
// trailing barrier; same-phase read/stage regions are disjoint (checked all
// phases). B-Q0 lives in reg set b0 (ph1), B-Q1 in b1 (ph2); phases 4/8 have
// zero LDS reads and overlap the counted vmcnt(4) drain.
//
// Blocks with blockIdx.y >= NY run NF4 dequant jobs instead (tail-fill).
//
// EPI: 0 = store bf16; 1 = x1 = res + v (fp32+bf16); 2 = out = res + v (fp32);
//      3 = gate/up interleaved -> h = silu(g)*u, bf16, h-col = gn/2.
template<int EPI>
__global__ __launch_bounds__(512, 2)
void gemm256_kernel(const unsigned short* __restrict__ Aact,
                    const unsigned short* __restrict__ Bw,
                    const unsigned short* __restrict__ tL,
                    const unsigned short* __restrict__ bL,
                    int K, int ldC,
                    const float* __restrict__ resIn,
                    float* __restrict__ outF,
                    unsigned short* __restrict__ outB,
                    int NY, DeqP dqa, DeqP dqb){
  if ((int)blockIdx.y >= NY){
    const int bid = ((int)blockIdx.y - NY) * gridDim.x + blockIdx.x;
    const int nb  = ((int)gridDim.y - NY) * gridDim.x;
    if (dqa.rows) deq_rows(dqa, bid, nb);
    if (dqb.rows) deq_rows(dqb, bid, nb);
    return;
  }
  __shared__ unsigned short As[4 * 8192];   // 4 regions x [128][64] bf16
  __shared__ unsigned short Bs[4 * 8192];
  const int tid  = threadIdx.x;
  const int lane = tid & 63;
  const int wave = tid >> 6;
  const int wm = wave >> 2, wn = wave & 3;
  const int q = lane >> 4, r15 = lane & 15;
  const int m0 = blockIdx.x << 8;   // x = M tiles so consecutive blocks share B-panel
  const int n0 = blockIdx.y << 8;

  const int nK = K >> 6;
  const int NT = nK + 1;            // + lora tile

  // ---- staging constants: chunk c = p*512+tid; lr = c>>3, slot = c&7 ----
  const int lr0  = tid >> 3;                     // 0..63 (p=1 adds 64)
  const int dc8  = ((tid & 7) ^ (lr0 & 7)) * 8;  // swizzled data col (shorts)
  const int ldsW = wave * 512;                   // wave chunk base (shorts)
  const int grB0 = (lr0 >> 5) * 64 + (lr0 & 31);

  auto stA = [&](int s, int db, int tt){
    const int gr = m0 + s * 64 + lr0;            // p=1 row = gr + 128
    const unsigned short* p; int ld;
    if (tt < nK){ p = Aact + (size_t)gr * K + (size_t)tt * 64 + dc8; ld = K; }
    else        { p = tL   + (size_t)gr * 64 + dc8;                  ld = 64; }
    unsigned short* d = As + (db * 2 + s) * 8192 + ldsW;
    gll16(p, d);
    gll16(p + (size_t)128 * ld, d + 4096);
  };
  auto stB = [&](int s, int db, int tt){
    const int gr = n0 + s * 32 + grB0;           // p=1 row = gr + 128
    const unsigned short* p; int ld;
    if (tt < nK){ p = Bw + (size_t)gr * K + (size_t)tt * 64 + dc8; ld = K; }
    else        { p = bL + (size_t)gr * 64 + dc8;                  ld = 64; }
    unsigned short* d = Bs + (db * 2 + s) * 8192 + ldsW;
    gll16(p, d);
    gll16(p + (size_t)128 * ld, d + 4096);
  };

  // ---- fragment read constants ----
  int arow[4], brow[2];
  #pragma unroll
  for (int i = 0; i < 4; ++i) arow[i] = (wm * 64 + i * 16 + r15) * 64;
  #pragma unroll
  for (int i = 0; i < 2; ++i) brow[i] = (wn * 32 + i * 16 + r15) * 64;
  const int swz0 = (q ^ (r15 & 7)) * 8;
  const int swz1 = ((4 + q) ^ (r15 & 7)) * 8;

  s16x8 a[4][2], b0[2][2], b1[2][2];
  auto loadA = [&](int mq, int db){
    const unsigned short* base = As + (db * 2 + mq) * 8192;
    #pragma unroll
    for (int fi = 0; fi < 4; ++fi){
      a[fi][0] = *(const s16x8*)(base + arow[fi] + swz0);
      a[fi][1] = *(const s16x8*)(base + arow[fi] + swz1);
    }
  };
  auto loadB = [&](int nq, int db, s16x8 (&bb)[2][2]){
    const unsigned short* base = Bs + (db * 2 + nq) * 8192;
    #pragma unroll
    for (int bi = 0; bi < 2; ++bi){
      bb[bi][0] = *(const s16x8*)(base + brow[bi] + swz0);
      bb[bi][1] = *(const s16x8*)(base + brow[bi] + swz1);
    }
  };

  f32x4 acc[8][4];
  #pragma unroll
  for (int i = 0; i < 8; ++i)
    #pragma unroll
    for (int j = 0; j < 4; ++j) acc[i][j] = (f32x4){0.f, 0.f, 0.f, 0.f};

  // ---- prologue: t0 {S0,Q0,Q1,S1} + t1 {S0,Q1}; wait t0 (4 newest in flight)
  stA(0, 0, 0); stB(0, 0, 0); stB(1, 0, 0); stA(1, 0, 0);
  stA(0, 1, 1); stB(1, 1, 1);
  asm volatile("s_waitcnt vmcnt(4)" ::: "memory");
  __builtin_amdgcn_s_barrier();

// R8: no leading barrier -- wave enters MFMA on its own lgkm drain; the
// trailing barrier (placed after, at call sites) carries all WAR protection.
#define PHASE_COMPUTE(MQ, NQ, BB)            \
  __builtin_amdgcn_s_setprio(1);             \
  mfma_quad<MQ, NQ>(acc, a, BB);             \
  __builtin_amdgcn_s_setprio(0)

  for (int t = 0; t + 1 < NT; t += 2){
    const int u2 = t + 2, u3 = t + 3;
    const bool h2 = u2 < NT, h3 = u3 < NT;

    // ---- tile t (buf 0) ----
    loadA(0, 0); loadB(0, 0, b0);
    stA(1, 1, t + 1);
    PHASE_COMPUTE(0, 0, b0);
    __builtin_amdgcn_s_barrier();

    loadB(1, 0, b1);
    stB(0, 1, t + 1);
    PHASE_COMPUTE(0, 1, b1);
    __builtin_amdgcn_s_barrier();

    loadA(1, 0);
    if (h2) stA(0, 0, u2);
    PHASE_COMPUTE(1, 1, b1);
    __builtin_amdgcn_s_barrier();

    if (h2) stB(1, 0, u2);
    PHASE_COMPUTE(1, 0, b0);                 // no LDS reads: b0 reused from regs
    if (h2) asm volatile("s_waitcnt vmcnt(4)" ::: "memory");
    else    asm volatile("s_waitcnt vmcnt(0)" ::: "memory");
    __builtin_amdgcn_s_barrier();

    // ---- tile t+1 (buf 1) ----
    loadA(0, 1); loadB(0, 1, b0);
    if (h2) stA(1, 0, u2);
    PHASE_COMPUTE(0, 0, b0);
    __builtin_amdgcn_s_barrier();

    loadB(1, 1, b1);
    if (h2) stB(0, 0, u2);
    PHASE_COMPUTE(0, 1, b1);
    __builtin_amdgcn_s_barrier();

    loadA(1, 1);
    if (h3) stA(0, 1, u3);
    PHASE_COMPUTE(1, 1, b1);
    __builtin_amdgcn_s_barrier();

    if (h3) stB(1, 1, u3);
    PHASE_COMPUTE(1, 0, b0);                 // no LDS reads
    if (h3) asm volatile("s_waitcnt vmcnt(4)" ::: "memory");
    else    asm volatile("s_waitcnt vmcnt(0)" ::: "memory");
    __builtin_amdgcn_s_barrier();
  }
#undef PHASE_COMPUTE

  // ---- tail tile (NT odd -> tile NT-1 in buf 0, fully landed) ----
  if (NT & 1){
    loadA(0, 0); loadB(0, 0, b0); mfma_quad<0, 0>(acc, a, b0);
    loadB(1, 0, b1);              mfma_quad<0, 1>(acc, a, b1);
    loadA(1, 0);                  mfma_quad<1, 1>(acc, a, b1);
                                  mfma_quad<1, 0>(acc, a, b0);
  }

  // ---- epilogue: D row m = q*4+reg, col n = lane&15 [measured m89] ----
  #pragma unroll
  for (int fi = 0; fi < 8; ++fi){
    const int gm = m0 + wm * 128 + fi * 16 + q * 4;
    #pragma unroll
    for (int bi = 0; bi < 4; ++bi){
      const int gn = n0 + wn * 64 + bi * 16 + r15;
      #pragma unroll
      for (int rr = 0; rr < 4; ++rr){
        const float v = acc[fi][bi][rr];
        if constexpr (EPI == 3){
          // gate/up pair in adjacent lanes: even lane = gate, odd = up
          const float other = __shfl_xor(v, 1);
          if ((r15 & 1) == 0){
            const float sg = v / (1.f + __expf(-v));
            outB[(size_t)(gm + rr) * ldC + (gn >> 1)] = f2bf(sg * other);
          }
        } else {
          const size_t idx = (size_t)(gm + rr) * ldC + gn;
          if constexpr (EPI == 0){
            outB[idx] = f2bf(v);
          } else if constexpr (EPI == 1){
            const float x1 = resIn[idx] + v;
            outF[idx] = x1;
            outB[idx] = f2bf(x1);
          } else {
            outF[idx] = resIn[idx] + v;
          }
        }
      }
    }
  }
}

// ---------------------------------------------------------------------------
extern "C" void kernel_launch(void* const* d_in, const int* in_sizes, int n_in,
                              void* d_out, int out_size, void* d_ws, size_t ws_size,
                              hipStream_t stream){
  (void)in_sizes; (void)n_in; (void)out_size; (void)ws_size;
  constexpr int M = 4096, H = 4096, I = 14336, I2 = 28672;
  constexpr int IH = 7168;     // half of I (Wgu dequant split across G1/G2)

  const float* x            = (const float*)d_in[0];
  const int*   codes_attn   = (const int*)  d_in[1];
  const float* scales_attn  = (const float*)d_in[2];
  const int*   codes_gu     = (const int*)  d_in[3];
  const float* scales_gu    = (const float*)d_in[4];
  const int*   codes_down   = (const int*)  d_in[5];
  const float* scales_down  = (const float*)d_in[6];
  const float* lora_A_h     = (const float*)d_in[7];
  const float* lora_A_down  = (const float*)d_in[8];
  const float* lora_B_attn  = (const float*)d_in[9];
  const float* lora_B_gu    = (const float*)d_in[10];
  const float* lora_B_down  = (const float*)d_in[11];
  float* out = (float*)d_out;

  char* ws = (char*)d_ws;
  size_t off = 0;
  auto take = [&](size_t b){ void* p = ws + off; off += b; return p; };
  unsigned short* xb    = (unsigned short*)take((size_t)M*H*2);    // x as bf16
  unsigned short* W1    = (unsigned short*)take((size_t)H*I*2);    // Wsum(HxH), later Wd(HxI)
  unsigned short* W2    = (unsigned short*)take((size_t)H*H*2);    // Wo (dequant rides G1)
  unsigned short* attn  = (unsigned short*)take((size_t)M*H*2);
  float*          x1f   = (float*)         take((size_t)M*H*4);
  unsigned short* x1b   = (unsigned short*)take((size_t)M*H*2);
  unsigned short* Wgu   = (unsigned short*)take((size_t)I2*H*2);   // gate/up row-interleaved
  unsigned short* hbuf  = (unsigned short*)take((size_t)M*I*2);
  unsigned short* t1    = (unsigned short*)take((size_t)M*64*2);   // zeroed arena starts here
  unsigned short* t2    = (unsigned short*)take((size_t)M*64*2);
  unsigned short* t3    = (unsigned short*)take((size_t)M*64*2);
  unsigned short* t4    = (unsigned short*)take((size_t)M*64*2);
  unsigned short* bl_at = (unsigned short*)take((size_t)H*64*2);
  unsigned short* bl_o  = (unsigned short*)take((size_t)H*64*2);
  unsigned short* bl_gu = (unsigned short*)take((size_t)I2*64*2);  // interleaved rows
  unsigned short* bl_dn = (unsigned short*)take((size_t)H*64*2);
  const size_t zbytes = (size_t)((char*)ws + off - (char*)t1);
  unsigned short* al_h  = (unsigned short*)take((size_t)6*16*H*2); // lora A (h-side) bf16
  unsigned short* al_dn = (unsigned short*)take((size_t)16*I*2);   // lora A down bf16

  // zero the t / bl arena (ws is poisoned 0xAA before every call)
  hipMemsetAsync(t1, 0, zbytes, stream);

  // casts
  cast_f32_bf16<<<dim3((M*(size_t)H/8)/256), 256, 0, stream>>>(xb, x, (long long)M*H/8);
  cast_f32_bf16<<<dim3(192), 256, 0, stream>>>(al_h,  lora_A_h,    (long long)6*16*H/8);
  cast_f32_bf16<<<dim3(112), 256, 0, stream>>>(al_dn, lora_A_down, (long long)16*I/8);

  // pack lora B panels into [N,64] bf16 (gu: row-interleaved to match Wgu)
  for (int p = 0; p < 3; ++p)
    pack_bl_kernel<<<dim3(256), 256, 0, stream>>>(bl_at, lora_B_attn + (size_t)p*H*16, H, p*16, 1.f/3.f, 1, 0);
  pack_bl_kernel<<<dim3(256), 256, 0, stream>>>(bl_o, lora_B_attn + (size_t)3*H*16, H, 0, 1.f, 1, 0);
  pack_bl_kernel<<<dim3(896), 256, 0, stream>>>(bl_gu, lora_B_gu, I, 0, 1.f, 2, 0);                    // gate -> rows 2j, cols 0-15
  pack_bl_kernel<<<dim3(896), 256, 0, stream>>>(bl_gu, lora_B_gu + (size_t)I*16, I, 16, 1.f, 2, 1);    // up   -> rows 2j+1, cols 16-31
  pack_bl_kernel<<<dim3(256), 256, 0, stream>>>(bl_dn, lora_B_down, H, 0, 1.f, 1, 0);

  // Wsum = (Wq+Wk+Wv)/3 (standalone: nothing to hide under yet)
  dequant3_kernel<<<dim3(H/2048, H), 256, 0, stream>>>(W1, codes_attn, scales_attn, H, 1.f/3.f);

  // t1 = xb @ [Aq;Ak;Av]^T  (one fused NP=3 pass; 1/3 folded into bl_at)
  lora_t_kernel<3><<<dim3(M/16), 256, 0, stream>>>(xb, al_h, t1, H, 0);

  const DeqP dq0{};  // empty
  // G1: attn = xb @ Wsum^T + lora. Rides: dequant Wo -> W2, Wgu lower half.
  {
    DeqP dWo { W2, codes_attn + (size_t)3*H*H, nullptr,
               scales_attn + (size_t)3*H*64, nullptr, H, H, 0 };
    DeqP dGuA{ Wgu, codes_gu, codes_gu + (size_t)I*H,
               scales_gu, scales_gu + (size_t)I*64, H, I, 1 };
    gemm256_kernel<0><<<dim3(16, 16 + 16), 512, 0, stream>>>(xb, W1, t1, bl_at, H, H,
                                                             nullptr, nullptr, attn, 16, dWo, dGuA);
  }

  // G2: x1 = x + attn @ Wo^T + lora. Rides: dequant Wgu upper half.
  lora_t_kernel<1><<<dim3(M/16), 256, 0, stream>>>(attn, al_h + (size_t)3*16*H, t2, H, 0);
  {
    DeqP dGuB{ Wgu + (size_t)I*H, codes_gu + (size_t)IH*H, codes_gu + (size_t)I*H + (size_t)IH*H,
               scales_gu + (size_t)IH*64, scales_gu + (size_t)I*64 + (size_t)IH*64, H, I, 1 };
    gemm256_kernel<1><<<dim3(16, 16 + 16), 512, 0, stream>>>(attn, W2, t2, bl_o, H, H,
                                                             x, x1f, x1b, 16, dGuB, dq0);
  }

  // G3: h = silu(g)*u fused epilogue over interleaved [Wg;Wu]. Rides: dequant Wd -> W1 slot.
  lora_t_kernel<2><<<dim3(M/16), 256, 0, stream>>>(x1b, al_h + (size_t)4*16*H, t3, H, 0);
  {
    DeqP dWd { W1, codes_down, nullptr, scales_down, nullptr, I, H, 0 };
    gemm256_kernel<3><<<dim3(16, 112 + 16), 512, 0, stream>>>(x1b, Wgu, t3, bl_gu, H, I,
                                                              nullptr, nullptr, hbuf, 112, dWd, dq0);
  }

  // G5: out = x1 + h @ Wd^T + lora
  lora_t_kernel<1><<<dim3(M/16), 256, 0, stream>>>(hbuf, al_dn, t4, I, 0);
  gemm256_kernel<2><<<dim3(16, 16), 512, 0, stream>>>(hbuf, W1, t4, bl_dn, I, H,
                                                      x1f, out, nullptr, 16, dq0, dq0);
}